// Round 6
// baseline (385.223 us; speedup 1.0000x reference)
//
#include <hip/hip_runtime.h>
#include <cstdint>
#include <cstddef>

// ---------- common ----------
typedef __bf16 bf16x8 __attribute__((ext_vector_type(8)));
typedef float  f32x4  __attribute__((ext_vector_type(4)));
typedef unsigned short u16x8 __attribute__((ext_vector_type(8)));

__device__ __forceinline__ uint16_t f2bf(float f) {
  uint32_t u = __float_as_uint(f);
  u += 0x7fffu + ((u >> 16) & 1u);          // round-to-nearest-even
  return (uint16_t)(u >> 16);
}
__device__ __forceinline__ float bf2f(uint16_t u) {
  return __uint_as_float((uint32_t)u << 16);
}

__device__ __forceinline__ f32x4 mfma16(bf16x8 a, bf16x8 b, f32x4 c) {
  return __builtin_amdgcn_mfma_f32_16x16x32_bf16(a, b, c, 0, 0, 0);
}

#define GLD_TO_LDS16(gptr, lptr)                                                   \
  __builtin_amdgcn_global_load_lds(                                                \
      (const __attribute__((address_space(1))) void*)(gptr),                       \
      (__attribute__((address_space(3))) void*)(lptr), 16, 0, 0)

// ---------- fused fp32 -> bf16 cast of all 4 tensors ----------
__global__ void cvt_all(const float* __restrict__ q, const float* __restrict__ k,
                        const float* __restrict__ w, const float* __restrict__ wo,
                        uint16_t* __restrict__ Xq, uint16_t* __restrict__ Xk,
                        uint16_t* __restrict__ Wb, uint16_t* __restrict__ Wob) {
  int i = blockIdx.x * blockDim.x + threadIdx.x;
  const float* src;
  uint16_t* dst;
  int off;
  if (i < 1048576)      { src = q;  dst = Xq;  off = i; }
  else if (i < 2097152) { src = k;  dst = Xk;  off = i - 1048576; }
  else if (i < 2883584) { src = w;  dst = Wb;  off = i - 2097152; }
  else                  { src = wo; dst = Wob; off = i - 2883584; }
  float4 v = ((const float4*)src)[off];
  ushort4 o;
  o.x = f2bf(v.x); o.y = f2bf(v.y); o.z = f2bf(v.z); o.w = f2bf(v.w);
  ((ushort4*)dst)[off] = o;
}

// ---------- pack hard (b,t,s) fp32 {0,1} -> bitmask, bit s%32 of word s/32 --
__global__ void bitpack(const float* __restrict__ hard, uint32_t* __restrict__ bits) {
  int i = blockIdx.x * 256 + threadIdx.x;  // one value per thread, 4M total
  unsigned long long m = __ballot(hard[i] != 0.0f);
  if ((threadIdx.x & 63) == 0) {
    int w = i >> 5;                        // lane0: i is 64-aligned
    bits[w]     = (uint32_t)m;
    bits[w + 1] = (uint32_t)(m >> 32);
  }
}

// ---------- fused Q + KV projection, 128x128 tiles, grid 768 (3 blk/CU) ----
__global__ __launch_bounds__(256)
void gemm_qkv(const uint16_t* __restrict__ Xq, const uint16_t* __restrict__ Xk,
              const uint16_t* __restrict__ Wb, const float* __restrict__ ipb,
              uint16_t* __restrict__ Qb, uint16_t* __restrict__ Kb,
              uint16_t* __restrict__ Vt) {
  __shared__ __align__(16) uint16_t As[128 * 32];
  __shared__ __align__(16) uint16_t Bs[128 * 32];
  const int tid  = threadIdx.x;
  const int wave = tid >> 6, lane = tid & 63;
  const int quad = lane >> 4, l16 = lane & 15;

  const int bid = blockIdx.x;
  const uint16_t *A, *B;
  const float* bias;
  int bm, bn, mode;
  if (bid < 256) {
    mode = 0; A = Xq; B = Wb; bias = ipb;
    bm = bid >> 3; bn = bid & 7;
  } else {
    mode = 1; A = Xk; B = Wb + (1 << 20); bias = ipb + 1024;
    int t = bid - 256; bm = t >> 4; bn = t & 15;
  }
  const int wm = (wave >> 1) << 6, wn = (wave & 1) << 6;
  const int K = 1024;

  f32x4 acc[4][4] = {};

  for (int k0 = 0; k0 < K; k0 += 32) {
    __syncthreads();
#pragma unroll
    for (int j = 0; j < 2; j++) {
      int c   = wave * 128 + j * 64 + lane;
      int row = c >> 2, kc = c & 3;
      const uint16_t* ga = A + (size_t)(bm * 128 + row) * K + k0 + kc * 8;
      GLD_TO_LDS16(ga, As + (size_t)(wave * 128 + j * 64) * 8);
      const uint16_t* gb = B + (size_t)(bn * 128 + row) * K + k0 + kc * 8;
      GLD_TO_LDS16(gb, Bs + (size_t)(wave * 128 + j * 64) * 8);
    }
    __syncthreads();

    bf16x8 af[4], bfr[4];
#pragma unroll
    for (int i = 0; i < 4; i++) {
      af[i]  = *(const bf16x8*)(As + (wm + i * 16 + l16) * 32 + quad * 8);
      bfr[i] = *(const bf16x8*)(Bs + (wn + i * 16 + l16) * 32 + quad * 8);
    }
#pragma unroll
    for (int mi = 0; mi < 4; mi++)
#pragma unroll
      for (int ni = 0; ni < 4; ni++)
        acc[mi][ni] = mfma16(af[mi], bfr[ni], acc[mi][ni]);
  }

#pragma unroll
  for (int mi = 0; mi < 4; mi++)
#pragma unroll
    for (int ni = 0; ni < 4; ni++)
#pragma unroll
      for (int r = 0; r < 4; r++) {
        int gi = bm * 128 + wm + mi * 16 + quad * 4 + r;  // row = t*4+b
        int gf = bn * 128 + wn + ni * 16 + l16;
        float c = acc[mi][ni][r] + bias[gf];
        if (mode == 0) {
          c *= 0.125f;  // HD^-0.5
          int t = gi >> 2, b = gi & 3, h = gf >> 6, d = gf & 63;
          Qb[((((size_t)b * 16 + h) * 1024 + t) << 6) + d] = f2bf(c);
        } else {
          int s = gi >> 2, b = gi & 3;
          if (gf < 1024) {
            int h = gf >> 6, d = gf & 63;
            Kb[((((size_t)b * 16 + h) * 1024 + s) << 6) + d] = f2bf(c);
          } else {
            int fv = gf - 1024, h = fv >> 6, d = fv & 63;
            Vt[((((size_t)b * 16 + h) * 64 + d) << 10) + s] = f2bf(c);
          }
        }
      }
}

// ---------- out-projection, 64x128 tiles, grid 512 (2 blk/CU) ----------
__global__ __launch_bounds__(256)
void gemm_out(const uint16_t* __restrict__ A, const uint16_t* __restrict__ B,
              const float* __restrict__ bias, float* __restrict__ o32) {
  __shared__ __align__(16) uint16_t As[64 * 32];
  __shared__ __align__(16) uint16_t Bs[128 * 32];
  const int tid  = threadIdx.x;
  const int wave = tid >> 6, lane = tid & 63;
  const int quad = lane >> 4, l16 = lane & 15;
  const int bm = blockIdx.x >> 3, bn = blockIdx.x & 7;  // 64 x 8 tiles
  const int wm = (wave >> 1) << 5, wn = (wave & 1) << 6;
  const int K = 1024;

  f32x4 acc[2][4] = {};

  for (int k0 = 0; k0 < K; k0 += 32) {
    __syncthreads();
    {
      int c   = wave * 64 + lane;       // A: 256 chunks, 1/thread
      int row = c >> 2, kc = c & 3;
      const uint16_t* ga = A + (size_t)(bm * 64 + row) * K + k0 + kc * 8;
      GLD_TO_LDS16(ga, As + (size_t)(wave * 64) * 8);
    }
#pragma unroll
    for (int j = 0; j < 2; j++) {       // B: 512 chunks, 2/thread
      int c   = wave * 128 + j * 64 + lane;
      int row = c >> 2, kc = c & 3;
      const uint16_t* gb = B + (size_t)(bn * 128 + row) * K + k0 + kc * 8;
      GLD_TO_LDS16(gb, Bs + (size_t)(wave * 128 + j * 64) * 8);
    }
    __syncthreads();

    bf16x8 af[2], bfr[4];
#pragma unroll
    for (int i = 0; i < 2; i++)
      af[i] = *(const bf16x8*)(As + (wm + i * 16 + l16) * 32 + quad * 8);
#pragma unroll
    for (int i = 0; i < 4; i++)
      bfr[i] = *(const bf16x8*)(Bs + (wn + i * 16 + l16) * 32 + quad * 8);
#pragma unroll
    for (int mi = 0; mi < 2; mi++)
#pragma unroll
      for (int ni = 0; ni < 4; ni++)
        acc[mi][ni] = mfma16(af[mi], bfr[ni], acc[mi][ni]);
  }

#pragma unroll
  for (int mi = 0; mi < 2; mi++)
#pragma unroll
    for (int ni = 0; ni < 4; ni++)
#pragma unroll
      for (int r = 0; r < 4; r++) {
        int gi = bm * 64 + wm + mi * 16 + quad * 4 + r;
        int gf = bn * 128 + wn + ni * 16 + l16;
        o32[(size_t)gi * 1024 + gf] = acc[mi][ni][r] + bias[gf];
      }
}

// ---------- attention: block = (b, h, t-tile64), grid 1024 ----------
// Each wave owns 16 t-rows completely: private P chunk buffer, private
// row-sums, NO __syncthreads anywhere. s processed in 8 chunks of 128.
// K/V slab per (b,h) read by only 16 blocks (vs 64 at t-tile16).
// Outputs: attn_out (t,b,h*64+d) bf16 ; rlout (b,h,t) fp32 = 1/rowsum.
__global__ __launch_bounds__(256, 2)
void attn_kernel(const uint16_t* __restrict__ qb, const uint16_t* __restrict__ kb,
                 const uint16_t* __restrict__ vtb, const uint32_t* __restrict__ bits,
                 uint16_t* __restrict__ attn_out, float* __restrict__ rlout) {
  __shared__ __align__(16) uint16_t P[4][16 * 140];  // per-wave, stride 140
  const int PS = 140;                                // 70 dw/row: write-conflict-free

  const int bid = blockIdx.x;           // 4b x 16h x 16tt
  const int b  = bid >> 8;
  const int h  = (bid >> 4) & 15;
  const int t0 = (bid & 15) << 6;
  const int tid = threadIdx.x, wave = tid >> 6, lane = tid & 63;
  const int quad = lane >> 4, l16 = lane & 15;
  const int tw = t0 + wave * 16;        // this wave's 16 t-rows
  const size_t bh = (size_t)b * 16 + h;
  uint16_t* Pw = P[wave];

  // Q A-frags for this wave's rows (m=l16, k=quad*8+j)
  const uint16_t* qrow = qb + ((bh << 10) + tw + l16) * 64;
  bf16x8 aq0 = *(const bf16x8*)(qrow + quad * 8);
  bf16x8 aq1 = *(const bf16x8*)(qrow + 32 + quad * 8);

  f32x4 acc[4] = {};                    // O: 4 d-tiles of 16, rows quad*4+r
  float sm[4] = {0.f, 0.f, 0.f, 0.f};   // per-lane row-sum partials

  for (int sc = 0; sc < 8; sc++) {
    // mask words for rows tw+quad*4+r, s-chunk sc, pre-shifted by l16:
    // bit for (r, n) = (wsh[r][n>>1] >> ((n&1)*16)) & 1
    uint32_t wsh[4][4];
#pragma unroll
    for (int r = 0; r < 4; r++) {
      uint4 u = *(const uint4*)(bits +
                 (((size_t)(b << 10) + tw + quad * 4 + r) << 5) + sc * 4);
      wsh[r][0] = u.x >> l16; wsh[r][1] = u.y >> l16;
      wsh[r][2] = u.z >> l16; wsh[r][3] = u.w >> l16;
    }

    // QK for this chunk: 8 n-tiles of 16 s; stream exp -> masked P
#pragma unroll
    for (int n = 0; n < 8; n++) {
      const uint16_t* krow = kb + ((bh << 10) + sc * 128 + n * 16 + l16) * 64;
      bf16x8 bk0 = *(const bf16x8*)(krow + quad * 8);
      bf16x8 bk1 = *(const bf16x8*)(krow + 32 + quad * 8);
      f32x4 c = {};
      c = mfma16(aq0, bk0, c);
      c = mfma16(aq1, bk1, c);
#pragma unroll
      for (int r = 0; r < 4; r++) {
        float e = __expf(c[r]);         // |score| small: safe without max-sub
        sm[r] += e;
        float em = ((wsh[r][n >> 1] >> ((n & 1) * 16)) & 1u) ? e : 0.f;
        Pw[(quad * 4 + r) * PS + n * 16 + l16] = f2bf(em);
      }
    }

    // PV for this chunk (wave-local LDS; in-order wave => no barrier)
#pragma unroll
    for (int kc = 0; kc < 4; kc++) {
      bf16x8 ap = *(const bf16x8*)(Pw + l16 * PS + kc * 32 + quad * 8);
#pragma unroll
      for (int dt = 0; dt < 4; dt++) {
        bf16x8 bv = *(const bf16x8*)(vtb + ((bh << 6) + dt * 16 + l16) * 1024 +
                                     sc * 128 + kc * 32 + quad * 8);
        acc[dt] = mfma16(ap, bv, acc[dt]);
      }
    }
  }

  // row-sums: reduce over l16 (s-columns); rl = 1/sum
  float rl[4];
#pragma unroll
  for (int r = 0; r < 4; r++) {
    float s = sm[r];
#pragma unroll
    for (int off = 1; off < 16; off <<= 1) s += __shfl_xor(s, off);
    rl[r] = 1.0f / s;
  }
  if (l16 == 0) {
#pragma unroll
    for (int r = 0; r < 4; r++)
      rlout[(bh << 10) + tw + quad * 4 + r] = rl[r];
  }

  // O epilogue
#pragma unroll
  for (int dt = 0; dt < 4; dt++)
#pragma unroll
    for (int r = 0; r < 4; r++) {
      float o = acc[dt][r] * rl[r];
      attn_out[((size_t)(tw + quad * 4 + r) * 4 + b) * 1024 +
               h * 64 + dt * 16 + l16] = f2bf(o);
    }
}

// ---------- avg: block = (b, t-tile64, s-tile64), grid 1024 ----------
// Recomputes QK per head (cheap MFMA), accumulates exp(S_h)*rl_h over all
// 16 heads in registers, applies hard mask once, writes final fp32 avg.
// No LDS, no barriers, no atomics.
__global__ __launch_bounds__(256, 2)
void avg_kernel(const uint16_t* __restrict__ qb, const uint16_t* __restrict__ kb,
                const float* __restrict__ rlin, const float* __restrict__ hard,
                float* __restrict__ avgout) {
  const int bid = blockIdx.x;           // 4b x 16tt x 16ss
  const int b  = bid >> 8;
  const int t0 = ((bid >> 4) & 15) << 6;
  const int s0 = (bid & 15) << 6;
  const int tid = threadIdx.x, wave = tid >> 6, lane = tid & 63;
  const int quad = lane >> 4, l16 = lane & 15;
  const int tw = t0 + wave * 16;

  // hard mask for this lane's positions (rows quad*4+r, cols n*16+l16)
  float msk[4][4];
#pragma unroll
  for (int n = 0; n < 4; n++)
#pragma unroll
    for (int r = 0; r < 4; r++)
      msk[n][r] = hard[((size_t)(b << 10) + tw + quad * 4 + r) * 1024 +
                       s0 + n * 16 + l16];

  float av[4][4] = {};

  for (int hh = 0; hh < 16; hh++) {
    const size_t bh = (size_t)b * 16 + hh;
    const uint16_t* qrow = qb + ((bh << 10) + tw + l16) * 64;
    bf16x8 aq0 = *(const bf16x8*)(qrow + quad * 8);
    bf16x8 aq1 = *(const bf16x8*)(qrow + 32 + quad * 8);
    float rl[4];
#pragma unroll
    for (int r = 0; r < 4; r++)
      rl[r] = rlin[(bh << 10) + tw + quad * 4 + r];
#pragma unroll
    for (int n = 0; n < 4; n++) {
      const uint16_t* krow = kb + ((bh << 10) + s0 + n * 16 + l16) * 64;
      bf16x8 bk0 = *(const bf16x8*)(krow + quad * 8);
      bf16x8 bk1 = *(const bf16x8*)(krow + 32 + quad * 8);
      f32x4 c = {};
      c = mfma16(aq0, bk0, c);
      c = mfma16(aq1, bk1, c);
#pragma unroll
      for (int r = 0; r < 4; r++)
        av[n][r] += __expf(c[r]) * rl[r];
    }
  }

#pragma unroll
  for (int n = 0; n < 4; n++)
#pragma unroll
    for (int r = 0; r < 4; r++)
      avgout[((size_t)(b << 10) + tw + quad * 4 + r) * 1024 + s0 + n * 16 + l16] =
          av[n][r] * msk[n][r] * 0.0625f;
}

// ---------- launch ----------
extern "C" void kernel_launch(void* const* d_in, const int* in_sizes, int n_in,
                              void* d_out, int out_size, void* d_ws, size_t ws_size,
                              hipStream_t stream) {
  const float* query = (const float*)d_in[0];
  const float* key   = (const float*)d_in[1];
  const float* hard  = (const float*)d_in[2];
  const float* ipw   = (const float*)d_in[3];
  const float* ipb   = (const float*)d_in[4];
  const float* opw   = (const float*)d_in[5];
  const float* opb   = (const float*)d_in[6];

  char* ws = (char*)d_ws;
  const size_t MB = 1ull << 20;
  uint16_t* Xq  = (uint16_t*)(ws + 0);        // 8 MB (reused as attn_out)
  uint16_t* Xk  = (uint16_t*)(ws + 8 * MB);   // 8 MB
  uint16_t* Wb  = (uint16_t*)(ws + 16 * MB);  // 6 MB
  uint16_t* Wob = (uint16_t*)(ws + 22 * MB);  // 2 MB
  uint16_t* Qb  = (uint16_t*)(ws + 24 * MB);  // 8 MB (b,h,t,d)
  uint16_t* Kb  = (uint16_t*)(ws + 32 * MB);  // 8 MB (b,h,s,d)
  uint16_t* Vt  = (uint16_t*)(ws + 40 * MB);  // 8 MB (b,h,d,s)
  uint16_t* AO  = Xq;                         // alias: Xq dead after gemm_qkv

  float* out = (float*)d_out;
  float* avg = out + 4194304;
  // bits (512 KB) + rlout (256 KB) parked in the out region: dead until
  // gemm_out, which runs last and overwrites them with the real output.
  uint32_t* bits  = (uint32_t*)out;
  float*    rlbuf = out + 131072;

  cvt_all<<<12288, 256, 0, stream>>>(query, key, ipw, opw, Xq, Xk, Wb, Wob);
  bitpack<<<16384, 256, 0, stream>>>(hard, bits);

  // fused Q-proj (256 blocks) + KV-proj (512 blocks)
  gemm_qkv<<<768, 256, 0, stream>>>(Xq, Xk, Wb, ipb, Qb, Kb, Vt);

  // attention (barrier-free, 64-row t-tiles): attn_out + 1/rowsum
  attn_kernel<<<1024, 256, 0, stream>>>(Qb, Kb, Vt, bits, AO, rlbuf);

  // head-averaged attention map (registers only, final fp32)
  avg_kernel<<<1024, 256, 0, stream>>>(Qb, Kb, rlbuf, hard, avg);

  // out = AO @ Wo^T + bias (fp32 direct to d_out; overwrites bits/rlbuf)
  gemm_out<<<512, 256, 0, stream>>>(AO, Wob, opb, out);
}

// Round 7
// 382.973 us; speedup vs baseline: 1.0059x; 1.0059x over previous
//
#include <hip/hip_runtime.h>
#include <cstdint>
#include <cstddef>

// ---------- common ----------
typedef __bf16 bf16x8 __attribute__((ext_vector_type(8)));
typedef float  f32x4  __attribute__((ext_vector_type(4)));
typedef unsigned short u16x8 __attribute__((ext_vector_type(8)));

__device__ __forceinline__ uint16_t f2bf(float f) {
  uint32_t u = __float_as_uint(f);
  u += 0x7fffu + ((u >> 16) & 1u);          // round-to-nearest-even
  return (uint16_t)(u >> 16);
}
__device__ __forceinline__ float bf2f(uint16_t u) {
  return __uint_as_float((uint32_t)u << 16);
}

__device__ __forceinline__ f32x4 mfma16(bf16x8 a, bf16x8 b, f32x4 c) {
  return __builtin_amdgcn_mfma_f32_16x16x32_bf16(a, b, c, 0, 0, 0);
}

#define GLD_TO_LDS16(gptr, lptr)                                                   \
  __builtin_amdgcn_global_load_lds(                                                \
      (const __attribute__((address_space(1))) void*)(gptr),                       \
      (__attribute__((address_space(3))) void*)(lptr), 16, 0, 0)

// ---------- fused fp32 -> bf16 cast of all 4 tensors ----------
__global__ void cvt_all(const float* __restrict__ q, const float* __restrict__ k,
                        const float* __restrict__ w, const float* __restrict__ wo,
                        uint16_t* __restrict__ Xq, uint16_t* __restrict__ Xk,
                        uint16_t* __restrict__ Wb, uint16_t* __restrict__ Wob) {
  int i = blockIdx.x * blockDim.x + threadIdx.x;
  const float* src;
  uint16_t* dst;
  int off;
  if (i < 1048576)      { src = q;  dst = Xq;  off = i; }
  else if (i < 2097152) { src = k;  dst = Xk;  off = i - 1048576; }
  else if (i < 2883584) { src = w;  dst = Wb;  off = i - 2097152; }
  else                  { src = wo; dst = Wob; off = i - 2883584; }
  float4 v = ((const float4*)src)[off];
  ushort4 o;
  o.x = f2bf(v.x); o.y = f2bf(v.y); o.z = f2bf(v.z); o.w = f2bf(v.w);
  ((ushort4*)dst)[off] = o;
}

// ---------- pack hard (b,t,s) fp32 {0,1} -> bitmask, bit s%32 of word s/32 --
__global__ void bitpack(const float* __restrict__ hard, uint32_t* __restrict__ bits) {
  int i = blockIdx.x * 256 + threadIdx.x;  // one value per thread, 4M total
  unsigned long long m = __ballot(hard[i] != 0.0f);
  if ((threadIdx.x & 63) == 0) {
    int w = i >> 5;                        // lane0: i is 64-aligned
    bits[w]     = (uint32_t)m;
    bits[w + 1] = (uint32_t)(m >> 32);
  }
}

// ---------- fused Q + KV projection, 128x128 tiles, grid 768 (3 blk/CU) ----
__global__ __launch_bounds__(256)
void gemm_qkv(const uint16_t* __restrict__ Xq, const uint16_t* __restrict__ Xk,
              const uint16_t* __restrict__ Wb, const float* __restrict__ ipb,
              uint16_t* __restrict__ Qb, uint16_t* __restrict__ Kb,
              uint16_t* __restrict__ Vt) {
  __shared__ __align__(16) uint16_t As[128 * 32];
  __shared__ __align__(16) uint16_t Bs[128 * 32];
  const int tid  = threadIdx.x;
  const int wave = tid >> 6, lane = tid & 63;
  const int quad = lane >> 4, l16 = lane & 15;

  const int bid = blockIdx.x;
  const uint16_t *A, *B;
  const float* bias;
  int bm, bn, mode;
  if (bid < 256) {
    mode = 0; A = Xq; B = Wb; bias = ipb;
    bm = bid >> 3; bn = bid & 7;
  } else {
    mode = 1; A = Xk; B = Wb + (1 << 20); bias = ipb + 1024;
    int t = bid - 256; bm = t >> 4; bn = t & 15;
  }
  const int wm = (wave >> 1) << 6, wn = (wave & 1) << 6;
  const int K = 1024;

  f32x4 acc[4][4] = {};

  for (int k0 = 0; k0 < K; k0 += 32) {
    __syncthreads();
#pragma unroll
    for (int j = 0; j < 2; j++) {
      int c   = wave * 128 + j * 64 + lane;
      int row = c >> 2, kc = c & 3;
      const uint16_t* ga = A + (size_t)(bm * 128 + row) * K + k0 + kc * 8;
      GLD_TO_LDS16(ga, As + (size_t)(wave * 128 + j * 64) * 8);
      const uint16_t* gb = B + (size_t)(bn * 128 + row) * K + k0 + kc * 8;
      GLD_TO_LDS16(gb, Bs + (size_t)(wave * 128 + j * 64) * 8);
    }
    __syncthreads();

    bf16x8 af[4], bfr[4];
#pragma unroll
    for (int i = 0; i < 4; i++) {
      af[i]  = *(const bf16x8*)(As + (wm + i * 16 + l16) * 32 + quad * 8);
      bfr[i] = *(const bf16x8*)(Bs + (wn + i * 16 + l16) * 32 + quad * 8);
    }
#pragma unroll
    for (int mi = 0; mi < 4; mi++)
#pragma unroll
      for (int ni = 0; ni < 4; ni++)
        acc[mi][ni] = mfma16(af[mi], bfr[ni], acc[mi][ni]);
  }

#pragma unroll
  for (int mi = 0; mi < 4; mi++)
#pragma unroll
    for (int ni = 0; ni < 4; ni++)
#pragma unroll
      for (int r = 0; r < 4; r++) {
        int gi = bm * 128 + wm + mi * 16 + quad * 4 + r;  // row = t*4+b
        int gf = bn * 128 + wn + ni * 16 + l16;
        float c = acc[mi][ni][r] + bias[gf];
        if (mode == 0) {
          c *= 0.125f;  // HD^-0.5
          int t = gi >> 2, b = gi & 3, h = gf >> 6, d = gf & 63;
          Qb[((((size_t)b * 16 + h) * 1024 + t) << 6) + d] = f2bf(c);
        } else {
          int s = gi >> 2, b = gi & 3;
          if (gf < 1024) {
            int h = gf >> 6, d = gf & 63;
            Kb[((((size_t)b * 16 + h) * 1024 + s) << 6) + d] = f2bf(c);
          } else {
            int fv = gf - 1024, h = fv >> 6, d = fv & 63;
            Vt[((((size_t)b * 16 + h) * 64 + d) << 10) + s] = f2bf(c);
          }
        }
      }
}

// ---------- out-projection, 64x128 tiles, grid 512 (2 blk/CU) ----------
__global__ __launch_bounds__(256)
void gemm_out(const uint16_t* __restrict__ A, const uint16_t* __restrict__ B,
              const float* __restrict__ bias, float* __restrict__ o32) {
  __shared__ __align__(16) uint16_t As[64 * 32];
  __shared__ __align__(16) uint16_t Bs[128 * 32];
  const int tid  = threadIdx.x;
  const int wave = tid >> 6, lane = tid & 63;
  const int quad = lane >> 4, l16 = lane & 15;
  const int bm = blockIdx.x >> 3, bn = blockIdx.x & 7;  // 64 x 8 tiles
  const int wm = (wave >> 1) << 5, wn = (wave & 1) << 6;
  const int K = 1024;

  f32x4 acc[2][4] = {};

  for (int k0 = 0; k0 < K; k0 += 32) {
    __syncthreads();
    {
      int c   = wave * 64 + lane;       // A: 256 chunks, 1/thread
      int row = c >> 2, kc = c & 3;
      const uint16_t* ga = A + (size_t)(bm * 64 + row) * K + k0 + kc * 8;
      GLD_TO_LDS16(ga, As + (size_t)(wave * 64) * 8);
    }
#pragma unroll
    for (int j = 0; j < 2; j++) {       // B: 512 chunks, 2/thread
      int c   = wave * 128 + j * 64 + lane;
      int row = c >> 2, kc = c & 3;
      const uint16_t* gb = B + (size_t)(bn * 128 + row) * K + k0 + kc * 8;
      GLD_TO_LDS16(gb, Bs + (size_t)(wave * 128 + j * 64) * 8);
    }
    __syncthreads();

    bf16x8 af[2], bfr[4];
#pragma unroll
    for (int i = 0; i < 2; i++)
      af[i] = *(const bf16x8*)(As + (wm + i * 16 + l16) * 32 + quad * 8);
#pragma unroll
    for (int i = 0; i < 4; i++)
      bfr[i] = *(const bf16x8*)(Bs + (wn + i * 16 + l16) * 32 + quad * 8);
#pragma unroll
    for (int mi = 0; mi < 2; mi++)
#pragma unroll
      for (int ni = 0; ni < 4; ni++)
        acc[mi][ni] = mfma16(af[mi], bfr[ni], acc[mi][ni]);
  }

#pragma unroll
  for (int mi = 0; mi < 2; mi++)
#pragma unroll
    for (int ni = 0; ni < 4; ni++)
#pragma unroll
      for (int r = 0; r < 4; r++) {
        int gi = bm * 64 + wm + mi * 16 + quad * 4 + r;
        int gf = bn * 128 + wn + ni * 16 + l16;
        o32[(size_t)gi * 1024 + gf] = acc[mi][ni][r] + bias[gf];
      }
}

// ---------- attention: XCD-swizzled (b,h,t-tile64), grid 1024 ----------
// R6 showed per-XCD working set = all 64 (b,h) slabs (24 MB) >> 4 MB L2:
// ~1 GB of scattered K/V reads served by L3 => 131 us with all pipes idle.
// Swizzle: dispatch is round-robin bid%8 -> XCD, so give each XCD 8 (b,h)
// slabs x 16 t-tiles => 3 MB working set, L2-resident.
// Barrier-free: each wave owns 16 t-rows (private P, private row-sums).
// Outputs: attn_out (t,b,h*64+d) bf16 ; rlout (b,h,t) fp32 = 1/rowsum.
__global__ __launch_bounds__(256, 2)
void attn_kernel(const uint16_t* __restrict__ qb, const uint16_t* __restrict__ kb,
                 const uint16_t* __restrict__ vtb, const uint32_t* __restrict__ bits,
                 uint16_t* __restrict__ attn_out, float* __restrict__ rlout) {
  __shared__ __align__(16) uint16_t P[4][16 * 140];  // per-wave, stride 140
  const int PS = 140;

  const int bid = blockIdx.x;
  const int xcd = bid & 7, j = bid >> 3;   // round-robin dispatch -> XCD
  const int slab = xcd * 8 + (j >> 4);     // 8 (b,h) slabs per XCD
  const int b = slab >> 4, h = slab & 15;
  const int t0 = (j & 15) << 6;
  const int tid = threadIdx.x, wave = tid >> 6, lane = tid & 63;
  const int quad = lane >> 4, l16 = lane & 15;
  const int tw = t0 + wave * 16;        // this wave's 16 t-rows
  const size_t bh = (size_t)b * 16 + h;
  uint16_t* Pw = P[wave];

  // Q A-frags for this wave's rows (m=l16, k=quad*8+j)
  const uint16_t* qrow = qb + ((bh << 10) + tw + l16) * 64;
  bf16x8 aq0 = *(const bf16x8*)(qrow + quad * 8);
  bf16x8 aq1 = *(const bf16x8*)(qrow + 32 + quad * 8);

  f32x4 acc[4] = {};                    // O: 4 d-tiles of 16, rows quad*4+r
  float sm[4] = {0.f, 0.f, 0.f, 0.f};   // per-lane row-sum partials

  for (int sc = 0; sc < 8; sc++) {
    // mask words for rows tw+quad*4+r, s-chunk sc, pre-shifted by l16
    uint32_t wsh[4][4];
#pragma unroll
    for (int r = 0; r < 4; r++) {
      uint4 u = *(const uint4*)(bits +
                 (((size_t)(b << 10) + tw + quad * 4 + r) << 5) + sc * 4);
      wsh[r][0] = u.x >> l16; wsh[r][1] = u.y >> l16;
      wsh[r][2] = u.z >> l16; wsh[r][3] = u.w >> l16;
    }

    // QK for this chunk: 8 n-tiles of 16 s; stream exp -> masked P
#pragma unroll
    for (int n = 0; n < 8; n++) {
      const uint16_t* krow = kb + ((bh << 10) + sc * 128 + n * 16 + l16) * 64;
      bf16x8 bk0 = *(const bf16x8*)(krow + quad * 8);
      bf16x8 bk1 = *(const bf16x8*)(krow + 32 + quad * 8);
      f32x4 c = {};
      c = mfma16(aq0, bk0, c);
      c = mfma16(aq1, bk1, c);
#pragma unroll
      for (int r = 0; r < 4; r++) {
        float e = __expf(c[r]);         // |score| small: safe without max-sub
        sm[r] += e;
        float em = ((wsh[r][n >> 1] >> ((n & 1) * 16)) & 1u) ? e : 0.f;
        Pw[(quad * 4 + r) * PS + n * 16 + l16] = f2bf(em);
      }
    }

    // PV for this chunk (wave-local LDS; in-order wave => no barrier)
#pragma unroll
    for (int kc = 0; kc < 4; kc++) {
      bf16x8 ap = *(const bf16x8*)(Pw + l16 * PS + kc * 32 + quad * 8);
#pragma unroll
      for (int dt = 0; dt < 4; dt++) {
        bf16x8 bv = *(const bf16x8*)(vtb + ((bh << 6) + dt * 16 + l16) * 1024 +
                                     sc * 128 + kc * 32 + quad * 8);
        acc[dt] = mfma16(ap, bv, acc[dt]);
      }
    }
  }

  // row-sums: reduce over l16 (s-columns); rl = 1/sum
  float rl[4];
#pragma unroll
  for (int r = 0; r < 4; r++) {
    float s = sm[r];
#pragma unroll
    for (int off = 1; off < 16; off <<= 1) s += __shfl_xor(s, off);
    rl[r] = 1.0f / s;
  }
  if (l16 == 0) {
#pragma unroll
    for (int r = 0; r < 4; r++)
      rlout[(bh << 10) + tw + quad * 4 + r] = rl[r];
  }

  // O epilogue
#pragma unroll
  for (int dt = 0; dt < 4; dt++)
#pragma unroll
    for (int r = 0; r < 4; r++) {
      float o = acc[dt][r] * rl[r];
      attn_out[((size_t)(tw + quad * 4 + r) * 4 + b) * 1024 +
               h * 64 + dt * 16 + l16] = f2bf(o);
    }
}

// ---------- avg: XCD-swizzled (b, t-tile64, s-tile64), grid 1024 ----------
// Each XCD owns (b = xcd/2, half the t-tiles, ALL s-tiles): working set =
// Q[b,:,t-half,:] 1 MB + K[b] 2 MB = 3 MB, L2-resident.
// Recomputes QK per head, accumulates exp(S_h)*rl_h over 16 heads in regs,
// masks once, writes final fp32 avg. No LDS, no barriers, no atomics.
__global__ __launch_bounds__(256, 2)
void avg_kernel(const uint16_t* __restrict__ qb, const uint16_t* __restrict__ kb,
                const float* __restrict__ rlin, const float* __restrict__ hard,
                float* __restrict__ avgout) {
  const int bid = blockIdx.x;
  const int xcd = bid & 7, j = bid >> 3;   // round-robin dispatch -> XCD
  const int b  = xcd >> 1;
  const int t0 = ((xcd & 1) * 8 + (j >> 4)) << 6;
  const int s0 = (j & 15) << 6;
  const int tid = threadIdx.x, wave = tid >> 6, lane = tid & 63;
  const int quad = lane >> 4, l16 = lane & 15;
  const int tw = t0 + wave * 16;

  // hard mask for this lane's positions (rows quad*4+r, cols n*16+l16)
  float msk[4][4];
#pragma unroll
  for (int n = 0; n < 4; n++)
#pragma unroll
    for (int r = 0; r < 4; r++)
      msk[n][r] = hard[((size_t)(b << 10) + tw + quad * 4 + r) * 1024 +
                       s0 + n * 16 + l16];

  float av[4][4] = {};

  for (int hh = 0; hh < 16; hh++) {
    const size_t bh = (size_t)b * 16 + hh;
    const uint16_t* qrow = qb + ((bh << 10) + tw + l16) * 64;
    bf16x8 aq0 = *(const bf16x8*)(qrow + quad * 8);
    bf16x8 aq1 = *(const bf16x8*)(qrow + 32 + quad * 8);
    float rl[4];
#pragma unroll
    for (int r = 0; r < 4; r++)
      rl[r] = rlin[(bh << 10) + tw + quad * 4 + r];
#pragma unroll
    for (int n = 0; n < 4; n++) {
      const uint16_t* krow = kb + ((bh << 10) + s0 + n * 16 + l16) * 64;
      bf16x8 bk0 = *(const bf16x8*)(krow + quad * 8);
      bf16x8 bk1 = *(const bf16x8*)(krow + 32 + quad * 8);
      f32x4 c = {};
      c = mfma16(aq0, bk0, c);
      c = mfma16(aq1, bk1, c);
#pragma unroll
      for (int r = 0; r < 4; r++)
        av[n][r] += __expf(c[r]) * rl[r];
    }
  }

#pragma unroll
  for (int n = 0; n < 4; n++)
#pragma unroll
    for (int r = 0; r < 4; r++)
      avgout[((size_t)(b << 10) + tw + quad * 4 + r) * 1024 + s0 + n * 16 + l16] =
          av[n][r] * msk[n][r] * 0.0625f;
}

// ---------- launch ----------
extern "C" void kernel_launch(void* const* d_in, const int* in_sizes, int n_in,
                              void* d_out, int out_size, void* d_ws, size_t ws_size,
                              hipStream_t stream) {
  const float* query = (const float*)d_in[0];
  const float* key   = (const float*)d_in[1];
  const float* hard  = (const float*)d_in[2];
  const float* ipw   = (const float*)d_in[3];
  const float* ipb   = (const float*)d_in[4];
  const float* opw   = (const float*)d_in[5];
  const float* opb   = (const float*)d_in[6];

  char* ws = (char*)d_ws;
  const size_t MB = 1ull << 20;
  uint16_t* Xq  = (uint16_t*)(ws + 0);        // 8 MB (reused as attn_out)
  uint16_t* Xk  = (uint16_t*)(ws + 8 * MB);   // 8 MB
  uint16_t* Wb  = (uint16_t*)(ws + 16 * MB);  // 6 MB
  uint16_t* Wob = (uint16_t*)(ws + 22 * MB);  // 2 MB
  uint16_t* Qb  = (uint16_t*)(ws + 24 * MB);  // 8 MB (b,h,t,d)
  uint16_t* Kb  = (uint16_t*)(ws + 32 * MB);  // 8 MB (b,h,s,d)
  uint16_t* Vt  = (uint16_t*)(ws + 40 * MB);  // 8 MB (b,h,d,s)
  uint16_t* AO  = Xq;                         // alias: Xq dead after gemm_qkv

  float* out = (float*)d_out;
  float* avg = out + 4194304;
  // bits (512 KB) + rlout (256 KB) parked in the out region: dead until
  // gemm_out, which runs last and overwrites them with the real output.
  uint32_t* bits  = (uint32_t*)out;
  float*    rlbuf = out + 131072;

  cvt_all<<<12288, 256, 0, stream>>>(query, key, ipw, opw, Xq, Xk, Wb, Wob);
  bitpack<<<16384, 256, 0, stream>>>(hard, bits);

  // fused Q-proj (256 blocks) + KV-proj (512 blocks)
  gemm_qkv<<<768, 256, 0, stream>>>(Xq, Xk, Wb, ipb, Qb, Kb, Vt);

  // attention (barrier-free, XCD-local K/V slabs): attn_out + 1/rowsum
  attn_kernel<<<1024, 256, 0, stream>>>(Qb, Kb, Vt, bits, AO, rlbuf);

  // head-averaged attention map (XCD-local Q/K, registers only)
  avg_kernel<<<1024, 256, 0, stream>>>(Qb, Kb, rlbuf, hard, avg);

  // out = AO @ Wo^T + bias (fp32 direct to d_out; overwrites bits/rlbuf)
  gemm_out<<<512, 256, 0, stream>>>(AO, Wob, opb, out);
}

// Round 8
// 270.132 us; speedup vs baseline: 1.4261x; 1.4177x over previous
//
#include <hip/hip_runtime.h>
#include <cstdint>
#include <cstddef>

// ---------- common ----------
typedef __bf16 bf16x8 __attribute__((ext_vector_type(8)));
typedef float  f32x4  __attribute__((ext_vector_type(4)));
typedef unsigned short u16x8 __attribute__((ext_vector_type(8)));

__device__ __forceinline__ uint16_t f2bf(float f) {
  uint32_t u = __float_as_uint(f);
  u += 0x7fffu + ((u >> 16) & 1u);          // round-to-nearest-even
  return (uint16_t)(u >> 16);
}
__device__ __forceinline__ float bf2f(uint16_t u) {
  return __uint_as_float((uint32_t)u << 16);
}

__device__ __forceinline__ f32x4 mfma16(bf16x8 a, bf16x8 b, f32x4 c) {
  return __builtin_amdgcn_mfma_f32_16x16x32_bf16(a, b, c, 0, 0, 0);
}

#define GLD_TO_LDS16(gptr, lptr)                                                   \
  __builtin_amdgcn_global_load_lds(                                                \
      (const __attribute__((address_space(1))) void*)(gptr),                       \
      (__attribute__((address_space(3))) void*)(lptr), 16, 0, 0)

// ---------- fused fp32 -> bf16 cast of all 4 tensors ----------
__global__ void cvt_all(const float* __restrict__ q, const float* __restrict__ k,
                        const float* __restrict__ w, const float* __restrict__ wo,
                        uint16_t* __restrict__ Xq, uint16_t* __restrict__ Xk,
                        uint16_t* __restrict__ Wb, uint16_t* __restrict__ Wob) {
  int i = blockIdx.x * blockDim.x + threadIdx.x;
  const float* src;
  uint16_t* dst;
  int off;
  if (i < 1048576)      { src = q;  dst = Xq;  off = i; }
  else if (i < 2097152) { src = k;  dst = Xk;  off = i - 1048576; }
  else if (i < 2883584) { src = w;  dst = Wb;  off = i - 2097152; }
  else                  { src = wo; dst = Wob; off = i - 2883584; }
  float4 v = ((const float4*)src)[off];
  ushort4 o;
  o.x = f2bf(v.x); o.y = f2bf(v.y); o.z = f2bf(v.z); o.w = f2bf(v.w);
  ((ushort4*)dst)[off] = o;
}

// ---------- pack hard (b,t,s) fp32 {0,1} -> bitmask ----------
__global__ void bitpack(const float* __restrict__ hard, uint32_t* __restrict__ bits) {
  int i = blockIdx.x * 256 + threadIdx.x;
  unsigned long long m = __ballot(hard[i] != 0.0f);
  if ((threadIdx.x & 63) == 0) {
    int w = i >> 5;
    bits[w]     = (uint32_t)m;
    bits[w + 1] = (uint32_t)(m >> 32);
  }
}

// ---------- fused Q + KV projection, 128x128 tiles, grid 768 ----------
__global__ __launch_bounds__(256)
void gemm_qkv(const uint16_t* __restrict__ Xq, const uint16_t* __restrict__ Xk,
              const uint16_t* __restrict__ Wb, const float* __restrict__ ipb,
              uint16_t* __restrict__ Qb, uint16_t* __restrict__ Kb,
              uint16_t* __restrict__ Vt) {
  __shared__ __align__(16) uint16_t As[128 * 32];
  __shared__ __align__(16) uint16_t Bs[128 * 32];
  const int tid  = threadIdx.x;
  const int wave = tid >> 6, lane = tid & 63;
  const int quad = lane >> 4, l16 = lane & 15;

  const int bid = blockIdx.x;
  const uint16_t *A, *B;
  const float* bias;
  int bm, bn, mode;
  if (bid < 256) {
    mode = 0; A = Xq; B = Wb; bias = ipb;
    bm = bid >> 3; bn = bid & 7;
  } else {
    mode = 1; A = Xk; B = Wb + (1 << 20); bias = ipb + 1024;
    int t = bid - 256; bm = t >> 4; bn = t & 15;
  }
  const int wm = (wave >> 1) << 6, wn = (wave & 1) << 6;
  const int K = 1024;

  f32x4 acc[4][4] = {};

  for (int k0 = 0; k0 < K; k0 += 32) {
    __syncthreads();
#pragma unroll
    for (int j = 0; j < 2; j++) {
      int c   = wave * 128 + j * 64 + lane;
      int row = c >> 2, kc = c & 3;
      const uint16_t* ga = A + (size_t)(bm * 128 + row) * K + k0 + kc * 8;
      GLD_TO_LDS16(ga, As + (size_t)(wave * 128 + j * 64) * 8);
      const uint16_t* gb = B + (size_t)(bn * 128 + row) * K + k0 + kc * 8;
      GLD_TO_LDS16(gb, Bs + (size_t)(wave * 128 + j * 64) * 8);
    }
    __syncthreads();

    bf16x8 af[4], bfr[4];
#pragma unroll
    for (int i = 0; i < 4; i++) {
      af[i]  = *(const bf16x8*)(As + (wm + i * 16 + l16) * 32 + quad * 8);
      bfr[i] = *(const bf16x8*)(Bs + (wn + i * 16 + l16) * 32 + quad * 8);
    }
#pragma unroll
    for (int mi = 0; mi < 4; mi++)
#pragma unroll
      for (int ni = 0; ni < 4; ni++)
        acc[mi][ni] = mfma16(af[mi], bfr[ni], acc[mi][ni]);
  }

#pragma unroll
  for (int mi = 0; mi < 4; mi++)
#pragma unroll
    for (int ni = 0; ni < 4; ni++)
#pragma unroll
      for (int r = 0; r < 4; r++) {
        int gi = bm * 128 + wm + mi * 16 + quad * 4 + r;  // row = t*4+b
        int gf = bn * 128 + wn + ni * 16 + l16;
        float c = acc[mi][ni][r] + bias[gf];
        if (mode == 0) {
          c *= 0.125f;  // HD^-0.5
          int t = gi >> 2, b = gi & 3, h = gf >> 6, d = gf & 63;
          Qb[((((size_t)b * 16 + h) * 1024 + t) << 6) + d] = f2bf(c);
        } else {
          int s = gi >> 2, b = gi & 3;
          if (gf < 1024) {
            int h = gf >> 6, d = gf & 63;
            Kb[((((size_t)b * 16 + h) * 1024 + s) << 6) + d] = f2bf(c);
          } else {
            int fv = gf - 1024, h = fv >> 6, d = fv & 63;
            Vt[((((size_t)b * 16 + h) * 64 + d) << 10) + s] = f2bf(c);
          }
        }
      }
}

// ---------- out-projection, 64x128 tiles, grid 512 ----------
__global__ __launch_bounds__(256)
void gemm_out(const uint16_t* __restrict__ A, const uint16_t* __restrict__ B,
              const float* __restrict__ bias, float* __restrict__ o32) {
  __shared__ __align__(16) uint16_t As[64 * 32];
  __shared__ __align__(16) uint16_t Bs[128 * 32];
  const int tid  = threadIdx.x;
  const int wave = tid >> 6, lane = tid & 63;
  const int quad = lane >> 4, l16 = lane & 15;
  const int bm = blockIdx.x >> 3, bn = blockIdx.x & 7;
  const int wm = (wave >> 1) << 5, wn = (wave & 1) << 6;
  const int K = 1024;

  f32x4 acc[2][4] = {};

  for (int k0 = 0; k0 < K; k0 += 32) {
    __syncthreads();
    {
      int c   = wave * 64 + lane;
      int row = c >> 2, kc = c & 3;
      const uint16_t* ga = A + (size_t)(bm * 64 + row) * K + k0 + kc * 8;
      GLD_TO_LDS16(ga, As + (size_t)(wave * 64) * 8);
    }
#pragma unroll
    for (int j = 0; j < 2; j++) {
      int c   = wave * 128 + j * 64 + lane;
      int row = c >> 2, kc = c & 3;
      const uint16_t* gb = B + (size_t)(bn * 128 + row) * K + k0 + kc * 8;
      GLD_TO_LDS16(gb, Bs + (size_t)(wave * 128 + j * 64) * 8);
    }
    __syncthreads();

    bf16x8 af[2], bfr[4];
#pragma unroll
    for (int i = 0; i < 2; i++)
      af[i] = *(const bf16x8*)(As + (wm + i * 16 + l16) * 32 + quad * 8);
#pragma unroll
    for (int i = 0; i < 4; i++)
      bfr[i] = *(const bf16x8*)(Bs + (wn + i * 16 + l16) * 32 + quad * 8);
#pragma unroll
    for (int mi = 0; mi < 2; mi++)
#pragma unroll
      for (int ni = 0; ni < 4; ni++)
        acc[mi][ni] = mfma16(af[mi], bfr[ni], acc[mi][ni]);
  }

#pragma unroll
  for (int mi = 0; mi < 2; mi++)
#pragma unroll
    for (int ni = 0; ni < 4; ni++)
#pragma unroll
      for (int r = 0; r < 4; r++) {
        int gi = bm * 64 + wm + mi * 16 + quad * 4 + r;
        int gf = bn * 128 + wn + ni * 16 + l16;
        o32[(size_t)gi * 1024 + gf] = acc[mi][ni][r] + bias[gf];
      }
}

// ---------- attention: (b,h,t64) XCD-swizzled, K/V staged in LDS ----------
// R7 proved L2-residency (FETCH 13 MB) with time unchanged: kernel is
// VMEM request-throughput bound (~73k cache lines/CU, 4x redundant across
// waves). Fix: stage K-chunk (16 KB) + V-chunk (16 KB) once per block into
// padded LDS (rows 72 / 136 elems: 16B-aligned, frag reads ~2-way = free),
// frags read from LDS. 2 barriers per s-chunk. LDS 53.8 KB -> 3 blocks/CU.
__global__ __launch_bounds__(256, 2)
void attn_kernel(const uint16_t* __restrict__ qb, const uint16_t* __restrict__ kb,
                 const uint16_t* __restrict__ vtb, const uint32_t* __restrict__ bits,
                 uint16_t* __restrict__ attn_out, float* __restrict__ rlout) {
  __shared__ __align__(16) uint16_t Ks[128 * 72];   // 18432 B, row=s, pad->72
  __shared__ __align__(16) uint16_t Vs[64 * 136];   // 17408 B, row=d, pad->136
  __shared__ __align__(16) uint16_t P[4][16 * 140]; // 17920 B, per-wave
  const int PS = 140;

  const int bid = blockIdx.x;
  const int xcd = bid & 7, j = bid >> 3;   // round-robin dispatch -> XCD
  const int slab = xcd * 8 + (j >> 4);     // 8 (b,h) slabs per XCD
  const int b = slab >> 4, h = slab & 15;
  const int t0 = (j & 15) << 6;
  const int tid = threadIdx.x, wave = tid >> 6, lane = tid & 63;
  const int quad = lane >> 4, l16 = lane & 15;
  const int tw = t0 + wave * 16;
  const size_t bh = (size_t)b * 16 + h;
  uint16_t* Pw = P[wave];

  // Q A-frags: per-wave-private rows -> direct global (no sharing to exploit)
  const uint16_t* qrow = qb + ((bh << 10) + tw + l16) * 64;
  bf16x8 aq0 = *(const bf16x8*)(qrow + quad * 8);
  bf16x8 aq1 = *(const bf16x8*)(qrow + 32 + quad * 8);

  f32x4 acc[4] = {};
  float sm[4] = {0.f, 0.f, 0.f, 0.f};

  // staging thread mapping (per 4 KB round)
  const int kRow = tid >> 3, kCol = (tid & 7) * 8;    // K: 32 rows/round
  const int vRow = tid >> 4, vCol = (tid & 15) * 8;   // V: 16 rows/round

  for (int sc = 0; sc < 8; sc++) {
    // coalesced global loads of this chunk into regs (issue before barrier)
    u16x8 kreg[4], vreg[4];
    const uint16_t* kbase = kb + (((bh << 10) + sc * 128) << 6);
#pragma unroll
    for (int r = 0; r < 4; r++)
      kreg[r] = *(const u16x8*)(kbase + (r * 256 + tid) * 8);
#pragma unroll
    for (int r = 0; r < 4; r++)
      vreg[r] = *(const u16x8*)(vtb + (((bh << 6) + r * 16 + vRow) << 10) +
                                sc * 128 + vCol);

    __syncthreads();  // prior chunk's LDS reads done
#pragma unroll
    for (int r = 0; r < 4; r++)
      *(u16x8*)(Ks + (r * 32 + kRow) * 72 + kCol) = kreg[r];
#pragma unroll
    for (int r = 0; r < 4; r++)
      *(u16x8*)(Vs + (r * 16 + vRow) * 136 + vCol) = vreg[r];
    __syncthreads();  // staging visible

    // mask words for rows tw+quad*4+r, pre-shifted by l16
    uint32_t wsh[4][4];
#pragma unroll
    for (int r = 0; r < 4; r++) {
      uint4 u = *(const uint4*)(bits +
                 (((size_t)(b << 10) + tw + quad * 4 + r) << 5) + sc * 4);
      wsh[r][0] = u.x >> l16; wsh[r][1] = u.y >> l16;
      wsh[r][2] = u.z >> l16; wsh[r][3] = u.w >> l16;
    }

    // QK from LDS: 8 n-tiles; stream exp -> masked P
#pragma unroll
    for (int n = 0; n < 8; n++) {
      const uint16_t* krow = Ks + (n * 16 + l16) * 72;
      bf16x8 bk0 = *(const bf16x8*)(krow + quad * 8);
      bf16x8 bk1 = *(const bf16x8*)(krow + 32 + quad * 8);
      f32x4 c = {};
      c = mfma16(aq0, bk0, c);
      c = mfma16(aq1, bk1, c);
#pragma unroll
      for (int r = 0; r < 4; r++) {
        float e = __expf(c[r]);
        sm[r] += e;
        float em = ((wsh[r][n >> 1] >> ((n & 1) * 16)) & 1u) ? e : 0.f;
        Pw[(quad * 4 + r) * PS + n * 16 + l16] = f2bf(em);
      }
    }

    // PV from LDS (P wave-private: no barrier)
#pragma unroll
    for (int kc = 0; kc < 4; kc++) {
      bf16x8 ap = *(const bf16x8*)(Pw + l16 * PS + kc * 32 + quad * 8);
#pragma unroll
      for (int dt = 0; dt < 4; dt++) {
        bf16x8 bv = *(const bf16x8*)(Vs + (dt * 16 + l16) * 136 +
                                     kc * 32 + quad * 8);
        acc[dt] = mfma16(ap, bv, acc[dt]);
      }
    }
  }

  // row-sums over l16; rl = 1/sum
  float rl[4];
#pragma unroll
  for (int r = 0; r < 4; r++) {
    float s = sm[r];
#pragma unroll
    for (int off = 1; off < 16; off <<= 1) s += __shfl_xor(s, off);
    rl[r] = 1.0f / s;
  }
  if (l16 == 0) {
#pragma unroll
    for (int r = 0; r < 4; r++)
      rlout[(bh << 10) + tw + quad * 4 + r] = rl[r];
  }

  // O epilogue
#pragma unroll
  for (int dt = 0; dt < 4; dt++)
#pragma unroll
    for (int r = 0; r < 4; r++) {
      float o = acc[dt][r] * rl[r];
      attn_out[((size_t)(tw + quad * 4 + r) * 4 + b) * 1024 +
               h * 64 + dt * 16 + l16] = f2bf(o);
    }
}

// ---------- avg: (b, t64, s128) XCD-swizzled, K staged in LDS ----------
// grid 512. Per head: stage K-tile (128 s-rows, 16 KB) once per block,
// Q direct (wave-private rows), accumulate exp(S_h)*rl_h over 16 heads in
// registers, mask from bits at the end.
__global__ __launch_bounds__(256, 2)
void avg_kernel(const uint16_t* __restrict__ qb, const uint16_t* __restrict__ kb,
                const float* __restrict__ rlin, const uint32_t* __restrict__ bits,
                float* __restrict__ avgout) {
  __shared__ __align__(16) uint16_t Ks[128 * 72];

  const int bid = blockIdx.x;
  const int xcd = bid & 7, j = bid >> 3;   // 512 blocks: xcd 0..7, j 0..63
  const int b  = xcd >> 1;
  const int t0 = ((xcd & 1) * 8 + (j >> 3)) << 6;
  const int s0 = (j & 7) << 7;
  const int tid = threadIdx.x, wave = tid >> 6, lane = tid & 63;
  const int quad = lane >> 4, l16 = lane & 15;
  const int tw = t0 + wave * 16;
  const int kRow = tid >> 3, kCol = (tid & 7) * 8;

  // mask words for rows tw+quad*4+r, cols [s0, s0+128), pre-shifted by l16
  uint32_t wsh[4][4];
#pragma unroll
  for (int r = 0; r < 4; r++) {
    uint4 u = *(const uint4*)(bits +
               (((size_t)(b << 10) + tw + quad * 4 + r) << 5) + (s0 >> 5));
    wsh[r][0] = u.x >> l16; wsh[r][1] = u.y >> l16;
    wsh[r][2] = u.z >> l16; wsh[r][3] = u.w >> l16;
  }

  float av[8][4] = {};

  for (int hh = 0; hh < 16; hh++) {
    const size_t bh = (size_t)b * 16 + hh;

    // stage this head's K-tile (rows s0..s0+127), coalesced
    u16x8 kreg[4];
    const uint16_t* kbase = kb + (((bh << 10) + s0) << 6);
#pragma unroll
    for (int r = 0; r < 4; r++)
      kreg[r] = *(const u16x8*)(kbase + (r * 256 + tid) * 8);
    __syncthreads();
#pragma unroll
    for (int r = 0; r < 4; r++)
      *(u16x8*)(Ks + (r * 32 + kRow) * 72 + kCol) = kreg[r];
    __syncthreads();

    // Q frags direct (wave-private rows), rl per row
    const uint16_t* qrow = qb + ((bh << 10) + tw + l16) * 64;
    bf16x8 aq0 = *(const bf16x8*)(qrow + quad * 8);
    bf16x8 aq1 = *(const bf16x8*)(qrow + 32 + quad * 8);
    float rl[4];
#pragma unroll
    for (int r = 0; r < 4; r++)
      rl[r] = rlin[(bh << 10) + tw + quad * 4 + r];

#pragma unroll
    for (int n = 0; n < 8; n++) {
      const uint16_t* krow = Ks + (n * 16 + l16) * 72;
      bf16x8 bk0 = *(const bf16x8*)(krow + quad * 8);
      bf16x8 bk1 = *(const bf16x8*)(krow + 32 + quad * 8);
      f32x4 c = {};
      c = mfma16(aq0, bk0, c);
      c = mfma16(aq1, bk1, c);
#pragma unroll
      for (int r = 0; r < 4; r++)
        av[n][r] += __expf(c[r]) * rl[r];
    }
  }

#pragma unroll
  for (int n = 0; n < 8; n++)
#pragma unroll
    for (int r = 0; r < 4; r++) {
      float m = ((wsh[r][n >> 1] >> ((n & 1) * 16)) & 1u) ? 0.0625f : 0.f;
      avgout[((size_t)(b << 10) + tw + quad * 4 + r) * 1024 +
             s0 + n * 16 + l16] = av[n][r] * m;
    }
}

// ---------- launch ----------
extern "C" void kernel_launch(void* const* d_in, const int* in_sizes, int n_in,
                              void* d_out, int out_size, void* d_ws, size_t ws_size,
                              hipStream_t stream) {
  const float* query = (const float*)d_in[0];
  const float* key   = (const float*)d_in[1];
  const float* hard  = (const float*)d_in[2];
  const float* ipw   = (const float*)d_in[3];
  const float* ipb   = (const float*)d_in[4];
  const float* opw   = (const float*)d_in[5];
  const float* opb   = (const float*)d_in[6];

  char* ws = (char*)d_ws;
  const size_t MB = 1ull << 20;
  uint16_t* Xq  = (uint16_t*)(ws + 0);        // 8 MB (reused as attn_out)
  uint16_t* Xk  = (uint16_t*)(ws + 8 * MB);   // 8 MB
  uint16_t* Wb  = (uint16_t*)(ws + 16 * MB);  // 6 MB
  uint16_t* Wob = (uint16_t*)(ws + 22 * MB);  // 2 MB
  uint16_t* Qb  = (uint16_t*)(ws + 24 * MB);  // 8 MB (b,h,t,d)
  uint16_t* Kb  = (uint16_t*)(ws + 32 * MB);  // 8 MB (b,h,s,d)
  uint16_t* Vt  = (uint16_t*)(ws + 40 * MB);  // 8 MB (b,h,d,s)
  uint16_t* AO  = Xq;                         // alias: Xq dead after gemm_qkv

  float* out = (float*)d_out;
  float* avg = out + 4194304;
  // bits (512 KB) + rlout (256 KB) parked in the out region: dead until
  // gemm_out, which runs last and overwrites them with the real output.
  uint32_t* bits  = (uint32_t*)out;
  float*    rlbuf = out + 131072;

  cvt_all<<<12288, 256, 0, stream>>>(query, key, ipw, opw, Xq, Xk, Wb, Wob);
  bitpack<<<16384, 256, 0, stream>>>(hard, bits);

  // fused Q-proj (256 blocks) + KV-proj (512 blocks)
  gemm_qkv<<<768, 256, 0, stream>>>(Xq, Xk, Wb, ipb, Qb, Kb, Vt);

  // attention (LDS-staged K/V, XCD-local slabs): attn_out + 1/rowsum
  attn_kernel<<<1024, 256, 0, stream>>>(Qb, Kb, Vt, bits, AO, rlbuf);

  // head-averaged attention map (LDS-staged K, XCD-local)
  avg_kernel<<<512, 256, 0, stream>>>(Qb, Kb, rlbuf, bits, avg);

  // out = AO @ Wo^T + bias (fp32 direct to d_out; overwrites bits/rlbuf)
  gemm_out<<<512, 256, 0, stream>>>(AO, Wob, opb, out);
}